// Round 2
// baseline (662.008 us; speedup 1.0000x reference)
//
#include <hip/hip_runtime.h>

#define HH   48
#define WW   48
#define NPIX 2304
#define CIN  32
#define COUT 64
#define KNB  29
#define FCO  16
#define NEVAL (KNB * 16)   // 464 MLP evals per pixel

__device__ __forceinline__ float swish_f(float x) {
    return x / (1.0f + __expf(-x));
}

// f64 Rodrigues matching reference so3_exp
__device__ __forceinline__ void so3_exp_d(double wx, double wy, double wz, double R[9]) {
    double n  = sqrt(wx * wx + wy * wy + wz * wz);
    double th = fmax(n, 1e-7);
    double kx = wx / th, ky = wy / th, kz = wz / th;
    double s = sin(th), c = cos(th);
    double omc = 1.0 - c;
    R[0] = 1.0 + omc * (kx * kx - 1.0);
    R[1] = -s * kz + omc * kx * ky;
    R[2] =  s * ky + omc * kx * kz;
    R[3] =  s * kz + omc * kx * ky;
    R[4] = 1.0 + omc * (ky * ky - 1.0);
    R[5] = -s * kx + omc * ky * kz;
    R[6] = -s * ky + omc * kz * kx;
    R[7] =  s * kx + omc * kz * ky;
    R[8] = 1.0 + omc * (kz * kz - 1.0);
}

// f64 fisheye lift rotation Rp for pixel p (matches reference _lift_log)
__device__ __forceinline__ void compute_Rp_d(int p, double R[9]) {
    int ui = p % WW, vi = p / WW;
    double dx = (double)ui - 23.5;
    double dy = (double)vi - 23.5;
    double r  = sqrt(dx * dx + dy * dy);
    const double FOCAL = 48.0 / 3.14159265358979323846;
    double theta = r / FOCAL;
    double rs = fmax(r, 1e-7);
    double st = sin(theta);
    double rayx = st * dx / rs;
    double rayy = st * dy / rs;
    double rayz = cos(theta);
    double pz  = fmin(fmax(rayz, -1.0 + 1e-6), 1.0 - 1e-6);
    double ang = acos(pz);
    double ax = -rayy, ay = rayx;               // axis (z comp = 0)
    double an = fmax(sqrt(ax * ax + ay * ay), 1e-7);
    ax /= an; ay /= an;
    so3_exp_d(ax * ang, ay * ang, 0.0, R);
}

__global__ __launch_bounds__(512)
void fisheye_kernel(const float* __restrict__ x, const int* __restrict__ nbr,
                    const float* __restrict__ W1, const float* __restrict__ b1,
                    const float* __restrict__ W2, const float* __restrict__ b2,
                    const float* __restrict__ W3, const float* __restrict__ b3,
                    const float* __restrict__ Wl, const float* __restrict__ bl,
                    float* __restrict__ out)
{
    __shared__ double s_Rq[9];
    __shared__ double s_Rn[KNB][9];
    __shared__ int    s_pj[KNB];
    __shared__ int    s_valid[KNB];
    __shared__ float  s_wts[NEVAL * 17];       // padded stride 17
    __shared__ float  s_S[KNB * FCO];
    __shared__ float  s_xv[2 * CIN * KNB];
    __shared__ float  s_T[2 * CIN * FCO];

    const int p = blockIdx.x;
    const int t = threadIdx.x;

    // ---- Phase A: lift rotations (f64) ----
    if (t == 0) {
        double R[9];
        compute_Rp_d(p, R);
        #pragma unroll
        for (int e = 0; e < 9; ++e) s_Rq[e] = R[e];
    }
    if (t < KNB) {
        int idx = nbr[p * KNB + t];
        int pj = max(idx, 0);
        s_pj[t] = pj;
        s_valid[t] = (idx >= 0) ? 1 : 0;
        double R[9];
        compute_Rp_d(pj, R);
        #pragma unroll
        for (int e = 0; e < 9; ++e) s_Rn[t][e] = R[e];
    }
    __syncthreads();

    // ---- Phase B: 464 rotation-log (f64) + MLP (f32) evals ----
    if (t < NEVAL) {
        int j  = t >> 4;
        int u  = t & 15;
        int l2 = u >> 2;   // neighbor-side lift
        int l1 = u & 3;    // query-side lift
        float* wdst = &s_wts[t * 17];
        if (!s_valid[j]) {
            #pragma unroll
            for (int f = 0; f < FCO; ++f) wdst[f] = 0.f;
        } else {
            // Effective lift E = Rp*Rz(l) for l in {0,1,3}; E = I for l==2
            // (reference's exp(log(.)) roundtrip collapses the exact-pi
            //  l==2 rotation to identity).
            double Ma[9], Mb[9];
            {
                double c1 = (l1 == 0) ? 1.0 : 0.0;
                double s1 = (l1 == 1) ? 1.0 : ((l1 == 3) ? -1.0 : 0.0);
                bool id1 = (l1 == 2);
                #pragma unroll
                for (int i = 0; i < 3; ++i) {
                    double a0 = s_Rq[i * 3 + 0], a1 = s_Rq[i * 3 + 1], a2 = s_Rq[i * 3 + 2];
                    Ma[i * 3 + 0] = id1 ? (i == 0 ? 1.0 : 0.0) : ( a0 * c1 + a1 * s1);
                    Ma[i * 3 + 1] = id1 ? (i == 1 ? 1.0 : 0.0) : (-a0 * s1 + a1 * c1);
                    Ma[i * 3 + 2] = id1 ? (i == 2 ? 1.0 : 0.0) : a2;
                }
                double c2 = (l2 == 0) ? 1.0 : 0.0;
                double s2 = (l2 == 1) ? 1.0 : ((l2 == 3) ? -1.0 : 0.0);
                bool id2 = (l2 == 2);
                #pragma unroll
                for (int i = 0; i < 3; ++i) {
                    double a0 = s_Rn[j][i * 3 + 0], a1 = s_Rn[j][i * 3 + 1], a2 = s_Rn[j][i * 3 + 2];
                    Mb[i * 3 + 0] = id2 ? (i == 0 ? 1.0 : 0.0) : ( a0 * c2 + a1 * s2);
                    Mb[i * 3 + 1] = id2 ? (i == 1 ? 1.0 : 0.0) : (-a0 * s2 + a1 * c2);
                    Mb[i * 3 + 2] = id2 ? (i == 2 ? 1.0 : 0.0) : a2;
                }
            }
            // C = Mb^T * Ma
            double C[9];
            #pragma unroll
            for (int i = 0; i < 3; ++i)
                #pragma unroll
                for (int jj = 0; jj < 3; ++jj) {
                    double acc = 0.0;
                    #pragma unroll
                    for (int kk = 0; kk < 3; ++kk)
                        acc += Mb[kk * 3 + i] * Ma[kk * 3 + jj];
                    C[i * 3 + jj] = acc;
                }
            // so3_log (reference formula incl. clipping), f64
            double tr   = C[0] + C[4] + C[8];
            double cosv = fmin(fmax((tr - 1.0) * 0.5, -1.0 + 1e-6), 1.0 - 1e-6);
            double th   = acos(cosv);
            double sv   = sin(th);
            double fac  = th / (2.0 * sv);
            float ab0 = (float)((C[7] - C[5]) * fac);
            float ab1 = (float)((C[2] - C[6]) * fac);
            float ab2 = (float)((C[3] - C[1]) * fac);
            // MLP 3->32->32->16 (f32); weight indices lane-uniform -> s_loads
            float h1[32];
            #pragma unroll
            for (int o = 0; o < 32; ++o)
                h1[o] = swish_f(b1[o] + ab0 * W1[o] + ab1 * W1[32 + o] + ab2 * W1[64 + o]);
            float h2[32];
            #pragma unroll
            for (int o = 0; o < 32; ++o) {
                float acc = b2[o];
                #pragma unroll
                for (int i = 0; i < 32; ++i) acc += h1[i] * W2[i * 32 + o];
                h2[o] = swish_f(acc);
            }
            #pragma unroll
            for (int f = 0; f < FCO; ++f) {
                float acc = b3[f];
                #pragma unroll
                for (int i = 0; i < 32; ++i) acc += h2[i] * W3[i * FCO + f];
                wdst[f] = swish_f(acc);
            }
        }
    } else {
        // threads 464..511 stage x values for this pixel's neighborhood
        for (int e = t - NEVAL; e < 2 * CIN * KNB; e += (512 - NEVAL)) {
            int bb  = e / (CIN * KNB);
            int rem = e - bb * (CIN * KNB);
            int c   = rem / KNB;
            int j   = rem - c * KNB;
            s_xv[e] = x[bb * (CIN * NPIX) + c * NPIX + s_pj[j]];
        }
    }
    __syncthreads();

    // ---- Phase C: S[j][f] = (1/L) * sum over (l1,l2) of wts ----
    if (t < NEVAL) {
        int j = t >> 4, f = t & 15;
        float acc = 0.f;
        #pragma unroll
        for (int u = 0; u < 16; ++u)
            acc += s_wts[(j * 16 + u) * 17 + f];
        s_S[j * FCO + f] = acc * 0.25f;
    }
    __syncthreads();

    // ---- Phase D: T[b][c][f] = sum_j xv[b][c][j] * S[j][f] ----
    for (int tt = t; tt < 2 * CIN * FCO; tt += 512) {
        int bb = tt >> 9;
        int c  = (tt >> 4) & 31;
        int f  = tt & 15;
        float acc = 0.f;
        #pragma unroll
        for (int j = 0; j < KNB; ++j)
            acc += s_xv[(bb * CIN + c) * KNB + j] * s_S[j * FCO + f];
        s_T[tt] = acc;
    }
    __syncthreads();

    // ---- Phase E: out[b,co,p] = sum_cf T[b][cf] * Wl[cf][co] + bl[co] ----
    if (t < 2 * COUT) {
        int bb = t >> 6, co = t & 63;
        float acc = bl[co];
        const float* Tb = &s_T[bb * (CIN * FCO)];
        #pragma unroll 8
        for (int cf = 0; cf < CIN * FCO; ++cf)
            acc += Tb[cf] * Wl[cf * COUT + co];
        out[bb * (COUT * NPIX) + co * NPIX + p] = acc;
    }
}

extern "C" void kernel_launch(void* const* d_in, const int* in_sizes, int n_in,
                              void* d_out, int out_size, void* d_ws, size_t ws_size,
                              hipStream_t stream) {
    const float* x  = (const float*)d_in[0];
    const int* nbr  = (const int*)d_in[1];
    const float* W1 = (const float*)d_in[2];
    const float* b1 = (const float*)d_in[3];
    const float* W2 = (const float*)d_in[4];
    const float* b2 = (const float*)d_in[5];
    const float* W3 = (const float*)d_in[6];
    const float* b3 = (const float*)d_in[7];
    const float* Wl = (const float*)d_in[8];
    const float* bl = (const float*)d_in[9];
    float* out = (float*)d_out;

    hipLaunchKernelGGL(fisheye_kernel, dim3(NPIX), dim3(512), 0, stream,
                       x, nbr, W1, b1, W2, b2, W3, b3, Wl, bl, out);
}

// Round 3
// 173.068 us; speedup vs baseline: 3.8251x; 3.8251x over previous
//
#include <hip/hip_runtime.h>

#define HH   48
#define WW   48
#define NPIX 2304
#define CIN  32
#define COUT 64
#define KNB  29
#define FCO  16
#define NEVAL (KNB * 16)   // 464 evals per pixel

__device__ __forceinline__ float swish_f(float x) {
    return x / (1.0f + __expf(-x));
}

// f64 Rodrigues matching reference so3_exp
__device__ __forceinline__ void so3_exp_d(double wx, double wy, double wz, double R[9]) {
    double n  = sqrt(wx * wx + wy * wy + wz * wz);
    double th = fmax(n, 1e-7);
    double kx = wx / th, ky = wy / th, kz = wz / th;
    double s = sin(th), c = cos(th);
    double omc = 1.0 - c;
    R[0] = 1.0 + omc * (kx * kx - 1.0);
    R[1] = -s * kz + omc * kx * ky;
    R[2] =  s * ky + omc * kx * kz;
    R[3] =  s * kz + omc * kx * ky;
    R[4] = 1.0 + omc * (ky * ky - 1.0);
    R[5] = -s * kx + omc * ky * kz;
    R[6] = -s * ky + omc * kz * kx;
    R[7] =  s * kx + omc * kz * ky;
    R[8] = 1.0 + omc * (kz * kz - 1.0);
}

// f64 fisheye lift rotation Rp for pixel p (matches reference _lift_log)
__device__ __forceinline__ void compute_Rp_d(int p, double R[9]) {
    int ui = p % WW, vi = p / WW;
    double dx = (double)ui - 23.5;
    double dy = (double)vi - 23.5;
    double r  = sqrt(dx * dx + dy * dy);
    const double FOCAL = 48.0 / 3.14159265358979323846;
    double theta = r / FOCAL;
    double rs = fmax(r, 1e-7);
    double st = sin(theta);
    double rayx = st * dx / rs;
    double rayy = st * dy / rs;
    double rayz = cos(theta);
    double pz  = fmin(fmax(rayz, -1.0 + 1e-6), 1.0 - 1e-6);
    double ang = acos(pz);
    double ax = -rayy, ay = rayx;               // axis (z comp = 0)
    double an = fmax(sqrt(ax * ax + ay * ay), 1e-7);
    ax /= an; ay /= an;
    so3_exp_d(ax * ang, ay * ang, 0.0, R);
}

__global__ __launch_bounds__(512, 4)
void fisheye_kernel(const float* __restrict__ x, const int* __restrict__ nbr,
                    const float* __restrict__ W1, const float* __restrict__ b1,
                    const float* __restrict__ W2, const float* __restrict__ b2,
                    const float* __restrict__ W3, const float* __restrict__ b3,
                    const float* __restrict__ Wl, const float* __restrict__ bl,
                    float* __restrict__ out)
{
    __shared__ double s_Rq[9];
    __shared__ double s_Rn[KNB][9];
    __shared__ double s_Rrel[KNB][9];          // Rn^T * Rq
    __shared__ int    s_pj[KNB];
    __shared__ int    s_valid[KNB];
    __shared__ float  s_wts[NEVAL * 17];       // padded stride 17
    __shared__ float  s_S[KNB * FCO];
    __shared__ float  s_xv[2 * CIN * KNB];
    __shared__ float  s_T[2 * CIN * FCO];

    const int p = blockIdx.x;
    const int t = threadIdx.x;

    // ---- Phase A: lift rotations (f64) ----
    if (t < KNB) {
        int idx = nbr[p * KNB + t];
        int pj = max(idx, 0);
        s_pj[t] = pj;
        s_valid[t] = (idx >= 0) ? 1 : 0;
        double R[9];
        compute_Rp_d(pj, R);
        #pragma unroll
        for (int e = 0; e < 9; ++e) s_Rn[t][e] = R[e];
    } else if (t == KNB) {
        double R[9];
        compute_Rp_d(p, R);
        #pragma unroll
        for (int e = 0; e < 9; ++e) s_Rq[e] = R[e];
    }
    __syncthreads();
    if (t < KNB) {
        // Rrel = Rn^T * Rq
        #pragma unroll
        for (int i = 0; i < 3; ++i)
            #pragma unroll
            for (int jj = 0; jj < 3; ++jj) {
                double acc = 0.0;
                #pragma unroll
                for (int kk = 0; kk < 3; ++kk)
                    acc += s_Rn[t][kk * 3 + i] * s_Rq[kk * 3 + jj];
                s_Rrel[t][i * 3 + jj] = acc;
            }
    }
    __syncthreads();

    // ---- Phase B: 464 evals; sign-permutation C + f64 log + streaming f32 MLP ----
    if (t < NEVAL) {
        int j  = t >> 4;
        int u  = t & 15;
        int l2 = u >> 2;   // neighbor-side lift
        int l1 = u & 3;    // query-side lift
        float* wdst = &s_wts[t * 17];
        if (!s_valid[j]) {
            #pragma unroll
            for (int f = 0; f < FCO; ++f) wdst[f] = 0.f;
        } else {
            // Effective lift E = Rp*Rz(l) for l in {0,1,3}; E = I for l==2
            // (reference's exp(log(.)) roundtrip collapses exact-pi l==2 to I).
            // C = E_b^T * E_a, built by sign/column permutation (90-deg Rz exact).
            float ab0, ab1, ab2;
            if (l1 == 2 && l2 == 2) {
                ab0 = ab1 = ab2 = 0.f;
            } else {
                double M[9];
                if (l1 != 2) {
                    const double* base = (l2 == 2) ? s_Rq : s_Rrel[j];
                    // M = base * Rz(l1): col-mix
                    if (l1 == 0) {
                        #pragma unroll
                        for (int i = 0; i < 3; ++i) {
                            M[i * 3 + 0] = base[i * 3 + 0];
                            M[i * 3 + 1] = base[i * 3 + 1];
                            M[i * 3 + 2] = base[i * 3 + 2];
                        }
                    } else if (l1 == 1) {
                        #pragma unroll
                        for (int i = 0; i < 3; ++i) {
                            M[i * 3 + 0] =  base[i * 3 + 1];
                            M[i * 3 + 1] = -base[i * 3 + 0];
                            M[i * 3 + 2] =  base[i * 3 + 2];
                        }
                    } else { // l1 == 3
                        #pragma unroll
                        for (int i = 0; i < 3; ++i) {
                            M[i * 3 + 0] = -base[i * 3 + 1];
                            M[i * 3 + 1] =  base[i * 3 + 0];
                            M[i * 3 + 2] =  base[i * 3 + 2];
                        }
                    }
                    if (l2 == 1) {        // rows: (r0,r1) <- (r1,-r0)
                        #pragma unroll
                        for (int jj = 0; jj < 3; ++jj) {
                            double r0 = M[0 * 3 + jj], r1 = M[1 * 3 + jj];
                            M[0 * 3 + jj] =  r1;
                            M[1 * 3 + jj] = -r0;
                        }
                    } else if (l2 == 3) { // rows: (r0,r1) <- (-r1,r0)
                        #pragma unroll
                        for (int jj = 0; jj < 3; ++jj) {
                            double r0 = M[0 * 3 + jj], r1 = M[1 * 3 + jj];
                            M[0 * 3 + jj] = -r1;
                            M[1 * 3 + jj] =  r0;
                        }
                    }
                } else {
                    // l1 == 2, l2 != 2: C = Rz(l2)^T * Rn^T
                    double Tm[9];
                    #pragma unroll
                    for (int i = 0; i < 3; ++i)
                        #pragma unroll
                        for (int jj = 0; jj < 3; ++jj)
                            Tm[i * 3 + jj] = s_Rn[j][jj * 3 + i];
                    if (l2 == 0) {
                        #pragma unroll
                        for (int e = 0; e < 9; ++e) M[e] = Tm[e];
                    } else if (l2 == 1) {
                        #pragma unroll
                        for (int jj = 0; jj < 3; ++jj) {
                            M[0 * 3 + jj] =  Tm[1 * 3 + jj];
                            M[1 * 3 + jj] = -Tm[0 * 3 + jj];
                            M[2 * 3 + jj] =  Tm[2 * 3 + jj];
                        }
                    } else { // l2 == 3
                        #pragma unroll
                        for (int jj = 0; jj < 3; ++jj) {
                            M[0 * 3 + jj] = -Tm[1 * 3 + jj];
                            M[1 * 3 + jj] =  Tm[0 * 3 + jj];
                            M[2 * 3 + jj] =  Tm[2 * 3 + jj];
                        }
                    }
                }
                // so3_log (reference formula incl. clipping), f64
                double tr   = M[0] + M[4] + M[8];
                double cosv = fmin(fmax((tr - 1.0) * 0.5, -1.0 + 1e-6), 1.0 - 1e-6);
                double th   = acos(cosv);
                double sv   = sqrt((1.0 - cosv) * (1.0 + cosv));  // == sin(th)
                double fac  = th / (2.0 * sv);
                ab0 = (float)((M[7] - M[5]) * fac);
                ab1 = (float)((M[2] - M[6]) * fac);
                ab2 = (float)((M[3] - M[1]) * fac);
            }
            // Streaming MLP 3->32->32->16 (f32), peak live ~48 VGPRs.
            float acc2[32];
            #pragma unroll
            for (int o = 0; o < 32; ++o) acc2[o] = b2[o];
            #pragma unroll
            for (int i = 0; i < 32; ++i) {
                float h = swish_f(b1[i] + ab0 * W1[i] + ab1 * W1[32 + i] + ab2 * W1[64 + i]);
                #pragma unroll
                for (int o = 0; o < 32; ++o) acc2[o] += h * W2[i * 32 + o];
            }
            float acc3[FCO];
            #pragma unroll
            for (int f = 0; f < FCO; ++f) acc3[f] = b3[f];
            #pragma unroll
            for (int o = 0; o < 32; ++o) {
                float h = swish_f(acc2[o]);
                #pragma unroll
                for (int f = 0; f < FCO; ++f) acc3[f] += h * W3[o * FCO + f];
            }
            #pragma unroll
            for (int f = 0; f < FCO; ++f) wdst[f] = swish_f(acc3[f]);
        }
    } else {
        // threads 464..511 stage x values for this pixel's neighborhood
        for (int e = t - NEVAL; e < 2 * CIN * KNB; e += (512 - NEVAL)) {
            int bb  = e / (CIN * KNB);
            int rem = e - bb * (CIN * KNB);
            int c   = rem / KNB;
            int j   = rem - c * KNB;
            s_xv[e] = x[bb * (CIN * NPIX) + c * NPIX + s_pj[j]];
        }
    }
    __syncthreads();

    // ---- Phase C: S[j][f] = (1/L) * sum over (l1,l2) of wts ----
    if (t < NEVAL) {
        int j = t >> 4, f = t & 15;
        float acc = 0.f;
        #pragma unroll
        for (int u = 0; u < 16; ++u)
            acc += s_wts[(j * 16 + u) * 17 + f];
        s_S[j * FCO + f] = acc * 0.25f;
    }
    __syncthreads();

    // ---- Phase D: T[b][c][f] = sum_j xv[b][c][j] * S[j][f] ----
    for (int tt = t; tt < 2 * CIN * FCO; tt += 512) {
        int bb = tt >> 9;
        int c  = (tt >> 4) & 31;
        int f  = tt & 15;
        float acc = 0.f;
        #pragma unroll
        for (int j = 0; j < KNB; ++j)
            acc += s_xv[(bb * CIN + c) * KNB + j] * s_S[j * FCO + f];
        s_T[tt] = acc;
    }
    __syncthreads();

    // ---- Phase E: out[b,co,p] = sum_cf T[b][cf] * Wl[cf][co] + bl[co] ----
    if (t < 2 * COUT) {
        int bb = t >> 6, co = t & 63;
        float acc = bl[co];
        const float* Tb = &s_T[bb * (CIN * FCO)];
        #pragma unroll 8
        for (int cf = 0; cf < CIN * FCO; ++cf)
            acc += Tb[cf] * Wl[cf * COUT + co];
        out[bb * (COUT * NPIX) + co * NPIX + p] = acc;
    }
}

extern "C" void kernel_launch(void* const* d_in, const int* in_sizes, int n_in,
                              void* d_out, int out_size, void* d_ws, size_t ws_size,
                              hipStream_t stream) {
    const float* x  = (const float*)d_in[0];
    const int* nbr  = (const int*)d_in[1];
    const float* W1 = (const float*)d_in[2];
    const float* b1 = (const float*)d_in[3];
    const float* W2 = (const float*)d_in[4];
    const float* b2 = (const float*)d_in[5];
    const float* W3 = (const float*)d_in[6];
    const float* b3 = (const float*)d_in[7];
    const float* Wl = (const float*)d_in[8];
    const float* bl = (const float*)d_in[9];
    float* out = (float*)d_out;

    hipLaunchKernelGGL(fisheye_kernel, dim3(NPIX), dim3(512), 0, stream,
                       x, nbr, W1, b1, W2, b2, W3, b3, Wl, bl, out);
}